// Round 1
// baseline (1035.607 us; speedup 1.0000x reference)
//
#include <hip/hip_runtime.h>
#include <cmath>

#define NROWS 65536
#define EDIM  1024
#define KST   4
#define LSTR  1032   // padded [d][e] stride: 1032*4 bytes, 16B-aligned per row

__global__ __launch_bounds__(256) void rvq_fused(
    const float* __restrict__ h_in,    // (N,1024)
    const float* __restrict__ W_proj,  // (4,5,1024)
    const float* __restrict__ b_proj,  // (4,5)
    const float* __restrict__ W_inv,   // (4,1024,5)
    const float* __restrict__ b_inv,   // (4,1024)
    const float* __restrict__ temp,    // (1)
    const float* __restrict__ u,       // (4,N,5,8)
    const float* __restrict__ p,       // (N)
    float* __restrict__ out_q,         // (N,1024)
    float* __restrict__ out_code,      // (N,20)
    float* __restrict__ out_loss,      // (1)
    float shift012, float shift3)
{
    __shared__ float sWp[5 * LSTR];
    __shared__ float sWi[5 * LSTR];
    __shared__ float sB[EDIM];

    const int tid  = threadIdx.x;
    const int lane = tid & 63;
    const int wib  = tid >> 6;
    const int wid  = blockIdx.x * 4 + wib;
    const int row0 = wid * 4;           // 4 rows per wave

    // ---- lane-role constants (d,c) grid for gumbel/argmax; lanes 40..63 duplicate d=4 ----
    int dl = lane >> 3; if (dl > 4) dl = 4;
    const int   cl     = lane & 7;
    const float stepf  = (float)(cl - 4);
    const bool  valid  = (dl < 3) || (dl == 3 && cl >= 1 && cl <= 6)
                                  || (dl == 4 && cl >= 2 && cl <= 6);
    const float shiftd = (dl < 3) ? shift012 : ((dl == 3) ? shift3 : 0.0f);
    const float halfld = (dl < 3) ? 3.4965f : ((dl == 3) ? 2.4975f : 1.998f);
    const float offd   = (dl == 4) ? 0.0f : 0.5f;
    const float invhwd = (dl < 3) ? 0.25f : ((dl == 3) ? (1.0f/3.0f) : 0.5f);
    const int   ulane  = (lane < 40) ? lane : 39;

    const float tval = temp[0];
    float te = fmaxf(tval * tval, 1e-8f);       // temp_eff
    const float inv_te  = 1.0f / te;            // == alpha
    const float alpham1 = inv_te - 1.0f;

    // ---- load rows: element e = 4*lane + 256*j ----
    float4 r4[4][4];
    float4 q4[4][4];
    float  p_r[4];
    float  ss[4];
    #pragma unroll
    for (int rr = 0; rr < 4; ++rr) {
        const float4* src = (const float4*)(h_in + (size_t)(row0 + rr) * EDIM);
        #pragma unroll
        for (int j = 0; j < 4; ++j) {
            r4[rr][j] = src[lane + 64 * j];
            q4[rr][j] = make_float4(0.f, 0.f, 0.f, 0.f);
        }
        p_r[rr] = p[row0 + rr];
        float s = 0.f;
        #pragma unroll
        for (int j = 0; j < 4; ++j) {
            s = fmaf(r4[rr][j].x, r4[rr][j].x, s);
            s = fmaf(r4[rr][j].y, r4[rr][j].y, s);
            s = fmaf(r4[rr][j].z, r4[rr][j].z, s);
            s = fmaf(r4[rr][j].w, r4[rr][j].w, s);
        }
        ss[rr] = (p_r[rr] <= 0.0f) ? s : 0.0f;   // p==0 edge: q_mix=0 -> ||h_in||
    }

    for (int i = 0; i < KST; ++i) {
        __syncthreads();   // protect LDS from previous stage's readers
        // ---- stage weights into LDS ----
        {
            const float4* gp = (const float4*)(W_proj + (size_t)i * 5120);
            #pragma unroll
            for (int k = 0; k < 5; ++k) {
                int t4 = tid + k * 256;            // 0..1279 float4s
                int d  = t4 >> 8;
                int e  = (t4 & 255) << 2;
                *(float4*)&sWp[d * LSTR + e] = gp[t4];
            }
            const float* gi = W_inv + (size_t)i * 5120;   // (1024,5) -> transpose to [d][e]
            for (int k = tid; k < 5120; k += 256) {
                int e = k / 5;
                int d = k - 5 * e;
                sWi[d * LSTR + e] = gi[k];
            }
            const float* gb = b_inv + (size_t)i * EDIM;
            #pragma unroll
            for (int k = 0; k < 4; ++k) sB[tid + k * 256] = gb[tid + k * 256];
        }
        __syncthreads();

        // ---- proj: h[d] = sum_e Wp[d][e] * r[e] ----
        float acc[5][4];
        #pragma unroll
        for (int d = 0; d < 5; ++d)
            #pragma unroll
            for (int rr = 0; rr < 4; ++rr) acc[d][rr] = 0.f;

        #pragma unroll
        for (int d = 0; d < 5; ++d) {
            #pragma unroll
            for (int j = 0; j < 4; ++j) {
                float4 w = *(const float4*)&sWp[d * LSTR + 4 * lane + 256 * j];
                #pragma unroll
                for (int rr = 0; rr < 4; ++rr) {
                    float a = acc[d][rr];
                    a = fmaf(w.x, r4[rr][j].x, a);
                    a = fmaf(w.y, r4[rr][j].y, a);
                    a = fmaf(w.z, r4[rr][j].z, a);
                    a = fmaf(w.w, r4[rr][j].w, a);
                    acc[d][rr] = a;
                }
            }
        }
        // butterfly reduce (all lanes end with full sum) + b_proj
        #pragma unroll
        for (int d = 0; d < 5; ++d) {
            float bp = b_proj[i * 5 + d];
            #pragma unroll
            for (int rr = 0; rr < 4; ++rr) {
                float v = acc[d][rr];
                v += __shfl_xor(v, 1);
                v += __shfl_xor(v, 2);
                v += __shfl_xor(v, 4);
                v += __shfl_xor(v, 8);
                v += __shfl_xor(v, 16);
                v += __shfl_xor(v, 32);
                acc[d][rr] = v + bp;
            }
        }

        // ---- bound + gumbel-argmax, lanes act as (d,c) pairs ----
        float zq_mine[4];
        #pragma unroll
        for (int rr = 0; rr < 4; ++rr) {
            float hsel = acc[0][rr];
            hsel = (dl == 1) ? acc[1][rr] : hsel;
            hsel = (dl == 2) ? acc[2][rr] : hsel;
            hsel = (dl == 3) ? acc[3][rr] : hsel;
            hsel = (dl == 4) ? acc[4][rr] : hsel;
            // z = tanh(h+shift)*half_l - offset, mul-then-sub like the reference
            float z  = __fsub_rn(__fmul_rn(tanhf(hsel + shiftd), halfld), offd);
            float uu = u[(size_t)i * 2621440 + (size_t)(row0 + rr) * 40 + ulane];
            float g1 = logf(uu + 1e-20f);
            float g  = -logf(-g1 + 1e-20f);
            float df = __fsub_rn(z, stepf);
            float d2 = __fmul_rn(df, df);
            d2 = valid ? d2 : 1e8f;
            float d2x = fmaf(alpham1, d2, d2);     // (alpha-1)*d2 + d2 (exact for temp=1)
            float y   = -(d2x * inv_te) + g;
            int   idx = cl;
            #pragma unroll
            for (int m = 1; m <= 4; m <<= 1) {     // argmax within 8-lane group, first-index ties
                float yo = __shfl_xor(y, m);
                int   io = __shfl_xor(idx, m);
                bool take = (yo > y) || (yo == y && io < idx);
                y   = take ? yo : y;
                idx = take ? io : idx;
            }
            zq_mine[rr] = (float)(idx - 4) * invhwd;  // steps[code]/half_width (ulp-exact)
        }
        // write codes (one lane per d)
        if (lane < 40 && cl == 0) {
            #pragma unroll
            for (int rr = 0; rr < 4; ++rr)
                out_code[(size_t)(row0 + rr) * 20 + i * 5 + dl] = zq_mine[rr];
        }
        // broadcast zq[d] to all lanes
        float zq[5][4];
        #pragma unroll
        for (int d = 0; d < 5; ++d)
            #pragma unroll
            for (int rr = 0; rr < 4; ++rr)
                zq[d][rr] = __shfl(zq_mine[rr], d * 8);

        // ---- inverse proj: q_i[e] = b_inv[e] + sum_d zq[d]*WiT[d][e] ----
        float4 qi[4][4];
        #pragma unroll
        for (int j = 0; j < 4; ++j) {
            float4 b = *(const float4*)&sB[4 * lane + 256 * j];
            #pragma unroll
            for (int rr = 0; rr < 4; ++rr) qi[rr][j] = b;
        }
        #pragma unroll
        for (int d = 0; d < 5; ++d) {
            #pragma unroll
            for (int j = 0; j < 4; ++j) {
                float4 w = *(const float4*)&sWi[d * LSTR + 4 * lane + 256 * j];
                #pragma unroll
                for (int rr = 0; rr < 4; ++rr) {
                    qi[rr][j].x = fmaf(zq[d][rr], w.x, qi[rr][j].x);
                    qi[rr][j].y = fmaf(zq[d][rr], w.y, qi[rr][j].y);
                    qi[rr][j].z = fmaf(zq[d][rr], w.z, qi[rr][j].z);
                    qi[rr][j].w = fmaf(zq[d][rr], w.w, qi[rr][j].w);
                }
            }
        }
        #pragma unroll
        for (int rr = 0; rr < 4; ++rr) {
            #pragma unroll
            for (int j = 0; j < 4; ++j) {
                r4[rr][j].x -= qi[rr][j].x;  q4[rr][j].x += qi[rr][j].x;
                r4[rr][j].y -= qi[rr][j].y;  q4[rr][j].y += qi[rr][j].y;
                r4[rr][j].z -= qi[rr][j].z;  q4[rr][j].z += qi[rr][j].z;
                r4[rr][j].w -= qi[rr][j].w;  q4[rr][j].w += qi[rr][j].w;
            }
        }
        // ---- loss snapshot: ||r||^2 at the selected stage (wave-uniform branch) ----
        const float lo = i * 0.25f, hi = (i + 1) * 0.25f;
        #pragma unroll
        for (int rr = 0; rr < 4; ++rr) {
            if (lo < p_r[rr] && p_r[rr] <= hi) {
                float s = 0.f;
                #pragma unroll
                for (int j = 0; j < 4; ++j) {
                    s = fmaf(r4[rr][j].x, r4[rr][j].x, s);
                    s = fmaf(r4[rr][j].y, r4[rr][j].y, s);
                    s = fmaf(r4[rr][j].z, r4[rr][j].z, s);
                    s = fmaf(r4[rr][j].w, r4[rr][j].w, s);
                }
                ss[rr] = s;
            }
        }
    }

    // ---- epilogue: store q, reduce loss ----
    #pragma unroll
    for (int rr = 0; rr < 4; ++rr) {
        float4* dst = (float4*)(out_q + (size_t)(row0 + rr) * EDIM);
        #pragma unroll
        for (int j = 0; j < 4; ++j) dst[lane + 64 * j] = q4[rr][j];
    }
    float lsum = 0.f;
    #pragma unroll
    for (int rr = 0; rr < 4; ++rr) {
        float v = ss[rr];
        v += __shfl_xor(v, 1);
        v += __shfl_xor(v, 2);
        v += __shfl_xor(v, 4);
        v += __shfl_xor(v, 8);
        v += __shfl_xor(v, 16);
        v += __shfl_xor(v, 32);
        lsum += sqrtf(v);
    }
    if (lane == 0) atomicAdd(out_loss, lsum * (1.0f / 65536.0f));
}

extern "C" void kernel_launch(void* const* d_in, const int* in_sizes, int n_in,
                              void* d_out, int out_size, void* d_ws, size_t ws_size,
                              hipStream_t stream) {
    (void)in_sizes; (void)n_in; (void)out_size; (void)d_ws; (void)ws_size;
    const float* h_in   = (const float*)d_in[0];
    const float* W_proj = (const float*)d_in[1];
    const float* b_proj = (const float*)d_in[2];
    const float* W_inv  = (const float*)d_in[3];
    const float* b_inv  = (const float*)d_in[4];
    const float* temp   = (const float*)d_in[5];
    const float* u      = (const float*)d_in[6];
    const float* p      = (const float*)d_in[7];

    float* out_q    = (float*)d_out;
    float* out_code = out_q + (size_t)NROWS * EDIM;
    float* out_loss = out_code + (size_t)NROWS * 20;

    // loss accumulator must start at 0 (d_out is poisoned before every call)
    hipMemsetAsync(out_loss, 0, sizeof(float), stream);

    // shift constants computed exactly as numpy does (f64 then cast)
    double hl01 = (8.0 - 1.0) * (1.0 - 1e-3) / 2.0;   // 3.4965
    double hl3  = (6.0 - 1.0) * (1.0 - 1e-3) / 2.0;   // 2.4975
    float shift012 = (float)std::tan(0.5 / hl01);
    float shift3   = (float)std::tan(0.5 / hl3);

    dim3 grid(NROWS / 16);   // 4 waves/block * 4 rows/wave
    dim3 block(256);
    hipLaunchKernelGGL(rvq_fused, grid, block, 0, stream,
                       h_in, W_proj, b_proj, W_inv, b_inv, temp, u, p,
                       out_q, out_code, out_loss, shift012, shift3);
}